// Round 1
// 1655.194 us; speedup vs baseline: 1.3201x; 1.3201x over previous
//
#include <hip/hip_runtime.h>
#include <hip/hip_bf16.h>
#include <stdint.h>
#include <stddef.h>

// Problem dims (fixed by reference)
#define HID   2048
#define INTER 8192
#define MOE_I 1024
#define TOK   8192   // B*S = 4*2048

using bf16 = __hip_bfloat16;
typedef __attribute__((ext_vector_type(8))) short short8;   // 8 bf16 = 4 VGPRs
typedef __attribute__((ext_vector_type(4))) float f32x4;

// ---------------------------------------------------------------------------
// async global -> LDS, 16B per lane (global_load_lds_dwordx4). LDS dest is
// wave-uniform base + lane*16; mapping l = base + tid*8 (bf16) matches.
// ---------------------------------------------------------------------------
__device__ __forceinline__ void gload_lds16(const bf16* g, bf16* l) {
    __builtin_amdgcn_global_load_lds(
        (const __attribute__((address_space(1))) void*)g,
        (__attribute__((address_space(3))) void*)l,
        16, 0, 0);
}

// 8x fp32 -> 8x bf16 packed (16 B)
__device__ __forceinline__ short8 cvt8(float4 a, float4 b) {
    union { short8 s; bf16 h[8]; } u;
    u.h[0] = __float2bfloat16(a.x); u.h[1] = __float2bfloat16(a.y);
    u.h[2] = __float2bfloat16(a.z); u.h[3] = __float2bfloat16(a.w);
    u.h[4] = __float2bfloat16(b.x); u.h[5] = __float2bfloat16(b.y);
    u.h[6] = __float2bfloat16(b.z); u.h[7] = __float2bfloat16(b.w);
    return u.s;
}

__global__ void cast_f32_to_bf16(const float* __restrict__ in,
                                 bf16* __restrict__ out, int n4) {
    int stride = gridDim.x * blockDim.x;
    for (int i = blockIdx.x * blockDim.x + threadIdx.x; i < n4; i += stride) {
        float4 v = reinterpret_cast<const float4*>(in)[i];
        union { uint64_t u; bf16 h[4]; } o;
        o.h[0] = __float2bfloat16(v.x); o.h[1] = __float2bfloat16(v.y);
        o.h[2] = __float2bfloat16(v.z); o.h[3] = __float2bfloat16(v.w);
        reinterpret_cast<uint64_t*>(out)[i] = o.u;
    }
}

// ---------------------------------------------------------------------------
// GEMM 1 (all-bf16, async staging): H = swish(X@Wg^T) * (X@Wu^T), bf16 out.
// X [M,K], Wg/Wu [N,K] row-major bf16 compact.
// R-occ fix: 128(M)x64(N) tile, BK=32, 4 waves (2Mx2N), dual acc [4][2]
// (64 acc regs vs previous 128) -> m97-class register budget -> ~3 waves/SIMD
// instead of 1. Structure (2-barrier, gload_lds staging) unchanged.
// ---------------------------------------------------------------------------
__global__ __launch_bounds__(256) void gemm_gu_bb(
    const bf16* __restrict__ X, const bf16* __restrict__ Wg,
    const bf16* __restrict__ Wu, bf16* __restrict__ H,
    int M, int N, int K)
{
    __shared__ bf16 sA[128 * 32];   // 8 KB
    __shared__ bf16 sG[64 * 32];    // 4 KB
    __shared__ bf16 sU[64 * 32];    // 4 KB

    const int tid  = threadIdx.x;
    const int lane = tid & 63;
    const int wave = tid >> 6;
    const int n0 = blockIdx.x * 64;
    const int m0 = blockIdx.y * 128;

    const int srow = tid >> 2;          // 0..63
    const int scol = (tid & 3) * 8;     // 0,8,16,24
    const bf16* ga = X  + (size_t)(m0 + srow) * K + scol;
    const bf16* gg = Wg + (size_t)(n0 + srow) * K + scol;
    const bf16* gu = Wu + (size_t)(n0 + srow) * K + scol;
    const size_t rowskip = (size_t)64 * K;
    bf16* la = sA + tid * 8;
    bf16* lg = sG + tid * 8;
    bf16* lu = sU + tid * 8;

    const int wm  = (wave >> 1) * 64;   // 0,64
    const int wn  = (wave & 1) * 32;    // 0,32
    const int r16 = lane & 15;
    const int kq8 = (lane >> 4) * 8;

    f32x4 accg[4][2] = {};
    f32x4 accu[4][2] = {};

    for (int k0 = 0; k0 < K; k0 += 32) {
        gload_lds16(ga,           la);
        gload_lds16(ga + rowskip, la + 2048);
        gload_lds16(gg,           lg);
        gload_lds16(gu,           lu);
        ga += 32; gg += 32; gu += 32;
        __syncthreads();   // barrier drains vmcnt -> staging complete

        short8 af[4], bg[2], bu[2];
#pragma unroll
        for (int i = 0; i < 4; i++)
            af[i] = *reinterpret_cast<const short8*>(sA + (wm + 16 * i + r16) * 32 + kq8);
#pragma unroll
        for (int j = 0; j < 2; j++) {
            bg[j] = *reinterpret_cast<const short8*>(sG + (wn + 16 * j + r16) * 32 + kq8);
            bu[j] = *reinterpret_cast<const short8*>(sU + (wn + 16 * j + r16) * 32 + kq8);
        }
#pragma unroll
        for (int i = 0; i < 4; i++)
#pragma unroll
            for (int j = 0; j < 2; j++) {
                accg[i][j] = __builtin_amdgcn_mfma_f32_16x16x32_bf16(af[i], bg[j], accg[i][j], 0, 0, 0);
                accu[i][j] = __builtin_amdgcn_mfma_f32_16x16x32_bf16(af[i], bu[j], accu[i][j], 0, 0, 0);
            }
        __syncthreads();
    }

    // epilogue: h = g*sigmoid(g)*u -> bf16. C/D: col=lane&15, row=(lane>>4)*4+r
#pragma unroll
    for (int i = 0; i < 4; i++) {
        const int rowb = m0 + wm + 16 * i + (lane >> 4) * 4;
#pragma unroll
        for (int j = 0; j < 2; j++) {
            const int col = n0 + wn + 16 * j + r16;
#pragma unroll
            for (int r = 0; r < 4; r++) {
                float g = accg[i][j][r];
                float u = accu[i][j][r];
                float h = g * u / (1.0f + __expf(-g));
                H[(size_t)(rowb + r) * N + col] = __float2bfloat16(h);
            }
        }
    }
}

// ---------------------------------------------------------------------------
// GEMM 1 fallback (fp32 inputs, fused cast staging) — same 128x64 geometry.
// ---------------------------------------------------------------------------
__global__ __launch_bounds__(256) void gemm_gu_f32(
    const float* __restrict__ X, const float* __restrict__ Wg,
    const float* __restrict__ Wu, bf16* __restrict__ H,
    int M, int N, int K)
{
    __shared__ bf16 sA[128 * 32];
    __shared__ bf16 sG[64 * 32];
    __shared__ bf16 sU[64 * 32];

    const int tid  = threadIdx.x;
    const int lane = tid & 63;
    const int wave = tid >> 6;
    const int n0 = blockIdx.x * 64;
    const int m0 = blockIdx.y * 128;

    const int srow = tid >> 2;
    const int scol = (tid & 3) * 8;

    const int wm  = (wave >> 1) * 64;
    const int wn  = (wave & 1) * 32;
    const int r16 = lane & 15;
    const int kq8 = (lane >> 4) * 8;

    f32x4 accg[4][2] = {};
    f32x4 accu[4][2] = {};

    for (int k0 = 0; k0 < K; k0 += 32) {
#pragma unroll
        for (int seg = 0; seg < 2; seg++) {
            const int row = srow + 64 * seg;
            const float* pa = X + (size_t)(m0 + row) * K + k0 + scol;
            float4 a0 = *(const float4*)pa, a1 = *(const float4*)(pa + 4);
            *(short8*)(sA + row * 32 + scol) = cvt8(a0, a1);
        }
        {
            const float* pg = Wg + (size_t)(n0 + srow) * K + k0 + scol;
            const float* pu = Wu + (size_t)(n0 + srow) * K + k0 + scol;
            float4 g0 = *(const float4*)pg, g1 = *(const float4*)(pg + 4);
            float4 u0 = *(const float4*)pu, u1 = *(const float4*)(pu + 4);
            *(short8*)(sG + srow * 32 + scol) = cvt8(g0, g1);
            *(short8*)(sU + srow * 32 + scol) = cvt8(u0, u1);
        }
        __syncthreads();

        short8 af[4], bg[2], bu[2];
#pragma unroll
        for (int i = 0; i < 4; i++)
            af[i] = *reinterpret_cast<const short8*>(sA + (wm + 16 * i + r16) * 32 + kq8);
#pragma unroll
        for (int j = 0; j < 2; j++) {
            bg[j] = *reinterpret_cast<const short8*>(sG + (wn + 16 * j + r16) * 32 + kq8);
            bu[j] = *reinterpret_cast<const short8*>(sU + (wn + 16 * j + r16) * 32 + kq8);
        }
#pragma unroll
        for (int i = 0; i < 4; i++)
#pragma unroll
            for (int j = 0; j < 2; j++) {
                accg[i][j] = __builtin_amdgcn_mfma_f32_16x16x32_bf16(af[i], bg[j], accg[i][j], 0, 0, 0);
                accu[i][j] = __builtin_amdgcn_mfma_f32_16x16x32_bf16(af[i], bu[j], accu[i][j], 0, 0, 0);
            }
        __syncthreads();
    }

#pragma unroll
    for (int i = 0; i < 4; i++) {
        const int rowb = m0 + wm + 16 * i + (lane >> 4) * 4;
#pragma unroll
        for (int j = 0; j < 2; j++) {
            const int col = n0 + wn + 16 * j + r16;
#pragma unroll
            for (int r = 0; r < 4; r++) {
                float g = accg[i][j][r];
                float u = accu[i][j][r];
                float h = g * u / (1.0f + __expf(-g));
                H[(size_t)(rowb + r) * N + col] = __float2bfloat16(h);
            }
        }
    }
}

// ---------------------------------------------------------------------------
// GEMM 2: OUT (+)= Ha @ Bs[:, col0:+Ka]^T  (+ Hb @ Br^T if Kb>0)
// A operands always bf16 (async). B operands per-phase: bf16 async (flag=1)
// or fp32 fused-cast (flag=0). acc: 0=overwrite, 1=accumulate.
// (Single-acc, m97-class budget — unchanged this round.)
// ---------------------------------------------------------------------------
__global__ __launch_bounds__(256) void gemm_down2(
    const bf16* __restrict__ Ha, const bf16* __restrict__ Bs16,
    const float* __restrict__ Bs32, int sflag, long ldBs, long col0,
    const bf16* __restrict__ Hb, const bf16* __restrict__ Br16,
    const float* __restrict__ Br32, int rflag, long ldBr,
    float* __restrict__ OUT, int M, int N, int Ka, int Kb, int acc)
{
    __shared__ bf16 sA[128 * 32];
    __shared__ bf16 sB[128 * 32];

    const int tid  = threadIdx.x;
    const int lane = tid & 63;
    const int wave = tid >> 6;
    const int n0 = blockIdx.x * 128;
    const int m0 = blockIdx.y * 128;

    const int srow = tid >> 2;
    const int scol = (tid & 3) * 8;
    bf16* la = sA + tid * 8;
    bf16* lb = sB + tid * 8;

    const int wm  = (wave >> 1) * 64;
    const int wn  = (wave & 1) * 64;
    const int r16 = lane & 15;
    const int kq8 = (lane >> 4) * 8;

    f32x4 acc4[4][4] = {};

    // ---- phase 1: shared ----
    {
        const bf16* ga = Ha + (size_t)(m0 + srow) * Ka + scol;
        const size_t rska = (size_t)64 * Ka;
        const bf16* gb = Bs16 + (size_t)(n0 + srow) * ldBs + col0 + scol;
        const size_t rskb = (size_t)64 * ldBs;
        for (int k0 = 0; k0 < Ka; k0 += 32) {
            gload_lds16(ga,        la);
            gload_lds16(ga + rska, la + 2048);
            ga += 32;
            if (sflag) {
                gload_lds16(gb,        lb);
                gload_lds16(gb + rskb, lb + 2048);
                gb += 32;
            } else {
#pragma unroll
                for (int seg = 0; seg < 2; seg++) {
                    const int row = srow + 64 * seg;
                    const float* pb = Bs32 + (size_t)(n0 + row) * ldBs + col0 + k0 + scol;
                    float4 b0 = *(const float4*)pb, b1 = *(const float4*)(pb + 4);
                    *(short8*)(sB + row * 32 + scol) = cvt8(b0, b1);
                }
            }
            __syncthreads();

            short8 af[4], bw[4];
#pragma unroll
            for (int i = 0; i < 4; i++)
                af[i] = *reinterpret_cast<const short8*>(sA + (wm + 16 * i + r16) * 32 + kq8);
#pragma unroll
            for (int j = 0; j < 4; j++)
                bw[j] = *reinterpret_cast<const short8*>(sB + (wn + 16 * j + r16) * 32 + kq8);
#pragma unroll
            for (int i = 0; i < 4; i++)
#pragma unroll
                for (int j = 0; j < 4; j++)
                    acc4[i][j] = __builtin_amdgcn_mfma_f32_16x16x32_bf16(af[i], bw[j], acc4[i][j], 0, 0, 0);
            __syncthreads();
        }
    }
    // ---- phase 2: routed (optional) ----
    if (Kb > 0) {
        const bf16* ga = Hb + (size_t)(m0 + srow) * Kb + scol;
        const size_t rska = (size_t)64 * Kb;
        const bf16* gb = Br16 + (size_t)(n0 + srow) * ldBr + scol;
        const size_t rskb = (size_t)64 * ldBr;
        for (int k0 = 0; k0 < Kb; k0 += 32) {
            gload_lds16(ga,        la);
            gload_lds16(ga + rska, la + 2048);
            ga += 32;
            if (rflag) {
                gload_lds16(gb,        lb);
                gload_lds16(gb + rskb, lb + 2048);
                gb += 32;
            } else {
#pragma unroll
                for (int seg = 0; seg < 2; seg++) {
                    const int row = srow + 64 * seg;
                    const float* pb = Br32 + (size_t)(n0 + row) * ldBr + k0 + scol;
                    float4 b0 = *(const float4*)pb, b1 = *(const float4*)(pb + 4);
                    *(short8*)(sB + row * 32 + scol) = cvt8(b0, b1);
                }
            }
            __syncthreads();

            short8 af[4], bw[4];
#pragma unroll
            for (int i = 0; i < 4; i++)
                af[i] = *reinterpret_cast<const short8*>(sA + (wm + 16 * i + r16) * 32 + kq8);
#pragma unroll
            for (int j = 0; j < 4; j++)
                bw[j] = *reinterpret_cast<const short8*>(sB + (wn + 16 * j + r16) * 32 + kq8);
#pragma unroll
            for (int i = 0; i < 4; i++)
#pragma unroll
                for (int j = 0; j < 4; j++)
                    acc4[i][j] = __builtin_amdgcn_mfma_f32_16x16x32_bf16(af[i], bw[j], acc4[i][j], 0, 0, 0);
            __syncthreads();
        }
    }

#pragma unroll
    for (int i = 0; i < 4; i++) {
        const int rowb = m0 + wm + 16 * i + (lane >> 4) * 4;
#pragma unroll
        for (int j = 0; j < 4; j++) {
            const int col = n0 + wn + 16 * j + r16;
#pragma unroll
            for (int r = 0; r < 4; r++) {
                const size_t idx = (size_t)(rowb + r) * N + col;
                float v = acc4[i][j][r];
                OUT[idx] = acc ? (OUT[idx] + v) : v;
            }
        }
    }
}

// ---------------------------------------------------------------------------
// launch: greedy ws allocation. Essentials: Xb,Gs,Us,Hr + min Hs chunk.
// Optionals (independent fallback): Ds, Gr, Ur, Dr. Hs chunk = remainder.
// ---------------------------------------------------------------------------
extern "C" void kernel_launch(void* const* d_in, const int* in_sizes, int n_in,
                              void* d_out, int out_size, void* d_ws, size_t ws_size,
                              hipStream_t stream) {
    const float* x       = (const float*)d_in[0];
    // d_in[1] = router_weight: dead (topk_idx < 8 always => comb_w == 1)
    const float* sh_gate = (const float*)d_in[2];
    const float* sh_up   = (const float*)d_in[3];
    const float* sh_down = (const float*)d_in[4];
    const float* r_gate  = (const float*)d_in[5];
    const float* r_up    = (const float*)d_in[6];
    const float* r_down  = (const float*)d_in[7];
    float* out = (float*)d_out;

    auto cast = [&](const float* in, bf16* o, size_t n) {
        int n4 = (int)(n / 4);
        int blocks = (n4 + 255) / 256;
        if (blocks > 2048) blocks = 2048;
        cast_f32_to_bf16<<<dim3(blocks), dim3(256), 0, stream>>>(in, o, n4);
    };

    const size_t HS_MIN = (size_t)TOK * 128 * 2;          // 2.1 MB
    size_t limit = (ws_size > HS_MIN) ? ws_size - HS_MIN : 0;
    size_t off = 0;
    auto take = [&](size_t bytes) -> bf16* {
        if (off + bytes <= limit) { bf16* p = (bf16*)((char*)d_ws + off); off += bytes; return p; }
        return nullptr;
    };

    bf16* Xb = take((size_t)TOK   * HID * 2);
    bf16* Gs = take((size_t)INTER * HID * 2);
    bf16* Us = take((size_t)INTER * HID * 2);
    bf16* Hr = take((size_t)TOK   * MOE_I * 2);

    if (Xb && Gs && Us && Hr) {
        bf16* Ds = take((size_t)INTER * HID * 2);
        bf16* Gr = take((size_t)MOE_I * HID * 2);
        bf16* Ur = take((size_t)MOE_I * HID * 2);
        bf16* Dr = take((size_t)MOE_I * HID * 2);

        // Hs chunk: largest divisor of INTER (multiple of 128) that fits
        size_t remain = ws_size - off;
        int Nc = 128;
        const int cands[7] = {8192, 4096, 2048, 1024, 512, 256, 128};
        for (int i = 0; i < 7; i++)
            if ((size_t)TOK * cands[i] * 2 <= remain) { Nc = cands[i]; break; }
        bf16* Hs = (bf16*)((char*)d_ws + off);

        cast(x,       Xb, (size_t)TOK   * HID);
        cast(sh_gate, Gs, (size_t)INTER * HID);
        cast(sh_up,   Us, (size_t)INTER * HID);
        if (Ds) cast(sh_down, Ds, (size_t)INTER * HID);
        if (Gr) cast(r_gate,  Gr, (size_t)MOE_I * HID);
        if (Ur) cast(r_up,    Ur, (size_t)MOE_I * HID);
        if (Dr) cast(r_down,  Dr, (size_t)MOE_I * HID);

        // routed intermediate
        if (Gr && Ur)
            gemm_gu_bb<<<dim3(MOE_I / 64, TOK / 128), dim3(256), 0, stream>>>(
                Xb, Gr, Ur, Hr, TOK, MOE_I, HID);
        else
            gemm_gu_f32<<<dim3(MOE_I / 64, TOK / 128), dim3(256), 0, stream>>>(
                x, r_gate, r_up, Hr, TOK, MOE_I, HID);

        const int nch = INTER / Nc;
        for (int c = 0; c < nch; c++) {
            gemm_gu_bb<<<dim3(Nc / 64, TOK / 128), dim3(256), 0, stream>>>(
                Xb, Gs + (size_t)c * Nc * HID, Us + (size_t)c * Nc * HID,
                Hs, TOK, Nc, HID);
            gemm_down2<<<dim3(HID / 128, TOK / 128), dim3(256), 0, stream>>>(
                Hs, Ds, sh_down, Ds ? 1 : 0, (long)INTER, (long)c * Nc,
                Hr, Dr, r_down, Dr ? 1 : 0, (long)MOE_I,
                out, TOK, HID, Nc, (c == 0) ? MOE_I : 0, (c == 0) ? 0 : 1);
        }
        return;
    }

    // ---- full fallback: fp32 fused-cast everywhere ----
    {
        const size_t hrBytes = (size_t)TOK * MOE_I * 2;
        int Nc = 128;
        const int cands[6] = {8192, 4096, 2048, 1024, 512, 256};
        for (int i = 0; i < 6; i++)
            if ((size_t)TOK * cands[i] * 2 + hrBytes <= ws_size) { Nc = cands[i]; break; }
        bf16* Hs = (bf16*)d_ws;
        bf16* Hr2 = Hs + (size_t)TOK * Nc;

        gemm_gu_f32<<<dim3(MOE_I / 64, TOK / 128), dim3(256), 0, stream>>>(
            x, r_gate, r_up, Hr2, TOK, MOE_I, HID);
        const int nch = INTER / Nc;
        for (int c = 0; c < nch; c++) {
            gemm_gu_f32<<<dim3(Nc / 64, TOK / 128), dim3(256), 0, stream>>>(
                x, sh_gate + (size_t)c * Nc * HID, sh_up + (size_t)c * Nc * HID,
                Hs, TOK, Nc, HID);
            gemm_down2<<<dim3(HID / 128, TOK / 128), dim3(256), 0, stream>>>(
                Hs, nullptr, sh_down, 0, (long)INTER, (long)c * Nc,
                Hr2, nullptr, r_down, 0, (long)MOE_I,
                out, TOK, HID, Nc, (c == 0) ? MOE_I : 0, (c == 0) ? 0 : 1);
        }
    }
}

// Round 2
// 1165.890 us; speedup vs baseline: 1.8742x; 1.4197x over previous
//
#include <hip/hip_runtime.h>
#include <hip/hip_bf16.h>
#include <stdint.h>
#include <stddef.h>

// Problem dims (fixed by reference)
#define HID   2048
#define INTER 8192
#define MOE_I 1024
#define TOK   8192   // B*S = 4*2048

using bf16 = __hip_bfloat16;
typedef __attribute__((ext_vector_type(8))) short short8;   // 8 bf16 = 4 VGPRs
typedef __attribute__((ext_vector_type(4))) float f32x4;

// ---------------------------------------------------------------------------
// async global -> LDS, 16B per lane (global_load_lds_dwordx4). LDS dest is
// wave-uniform base + lane*16; per-lane pointers with lane-stride 16 match.
// ---------------------------------------------------------------------------
__device__ __forceinline__ void gload_lds16(const bf16* g, bf16* l) {
    __builtin_amdgcn_global_load_lds(
        (const __attribute__((address_space(1))) void*)g,
        (__attribute__((address_space(3))) void*)l,
        16, 0, 0);
}

// 8x fp32 -> 8x bf16 packed (16 B)
__device__ __forceinline__ short8 cvt8(float4 a, float4 b) {
    union { short8 s; bf16 h[8]; } u;
    u.h[0] = __float2bfloat16(a.x); u.h[1] = __float2bfloat16(a.y);
    u.h[2] = __float2bfloat16(a.z); u.h[3] = __float2bfloat16(a.w);
    u.h[4] = __float2bfloat16(b.x); u.h[5] = __float2bfloat16(b.y);
    u.h[6] = __float2bfloat16(b.z); u.h[7] = __float2bfloat16(b.w);
    return u.s;
}

__global__ void cast_f32_to_bf16(const float* __restrict__ in,
                                 bf16* __restrict__ out, int n4) {
    int stride = gridDim.x * blockDim.x;
    for (int i = blockIdx.x * blockDim.x + threadIdx.x; i < n4; i += stride) {
        float4 v = reinterpret_cast<const float4*>(in)[i];
        union { uint64_t u; bf16 h[4]; } o;
        o.h[0] = __float2bfloat16(v.x); o.h[1] = __float2bfloat16(v.y);
        o.h[2] = __float2bfloat16(v.z); o.h[3] = __float2bfloat16(v.w);
        reinterpret_cast<uint64_t*>(out)[i] = o.u;
    }
}

// ===========================================================================
// Deep-pipelined GEMMs (T2 swizzle + T3/T4 counted vmcnt + T5 setprio).
// Ring of 3 LDS slots, BK=64 sub-tiles, 512 threads / 8 waves, prefetch
// distance 2 sub-tiles, 6 global_load_lds per wave per sub-tile,
// s_waitcnt vmcnt(6) + one s_barrier per sub-tile (never vmcnt(0) in loop).
//
// LDS rows are 64 bf16 = 128 B. Swizzle: 16-B octet o at row r stored at
// physical octet o ^ (r&7). Staging pre-swizzles the per-lane GLOBAL source
// (global_load_lds writes linearly); ds_read applies the same XOR. Gives
// 2-way (free) bank access on ds_read_b128.
// ===========================================================================

// ---------------------------------------------------------------------------
// gemm8_gu: H = swish(X@Wg^T) * (X@Wu^T), bf16. X[M,K], Wg/Wu[N,K] bf16.
// Tile BM=128 x BN=128, waves 2M x 4N, per-wave dual 64x32 output.
// LDS slot = A(128x64) + G(128x64) + U(128x64) = 48 KB; 3 slots = 144 KB.
// ---------------------------------------------------------------------------
__global__ __launch_bounds__(512) void gemm8_gu(
    const bf16* __restrict__ X, const bf16* __restrict__ Wg,
    const bf16* __restrict__ Wu, bf16* __restrict__ H,
    int M, int N, int K)
{
    constexpr int STRM = 128 * 64;        // elements per stream tile (8192)
    constexpr int SLOT = 3 * STRM;        // elements per ring slot
    __shared__ __align__(16) bf16 lds[3 * SLOT];   // 144 KB

    const int tid  = threadIdx.x;
    const int lane = tid & 63;
    const int wave = tid >> 6;
    const int n0 = blockIdx.x * 128;
    const int m0 = blockIdx.y * 128;

    // staging: lane t covers (row = t>>3 within 64-row half, octet = t&7).
    // pre-swizzled global col = ((t&7) ^ (row&7)) * 8 elements.
    const int srow = tid >> 3;                          // 0..63
    const int scol = (((tid & 7) ^ (srow & 7)) << 3);   // 0..56
    const bf16* pA = X  + (size_t)(m0 + srow) * K + scol;
    const bf16* pG = Wg + (size_t)(n0 + srow) * K + scol;
    const bf16* pU = Wu + (size_t)(n0 + srow) * K + scol;
    const size_t rsk = (size_t)64 * K;                  // +64 rows
    bf16* dl = lds + tid * 8;                           // lane LDS dest

    // compute-side
    const int wm = (wave >> 2) * 64;   // 0,64
    const int wn = (wave & 3) * 32;    // 0,32,64,96
    const int r16 = lane & 15;
    const int kq  = lane >> 4;         // 0..3
    const int cswz0 = ((kq       ^ (lane & 7)) << 4);   // ks=0 byte col
    const int cswz1 = (((4 + kq) ^ (lane & 7)) << 4);   // ks=1 byte col
    const char* lb = (const char*)lds;

    int roffA[4], roffW[2];
#pragma unroll
    for (int i = 0; i < 4; i++) roffA[i] = (wm + 16 * i + r16) * 128;
#pragma unroll
    for (int j = 0; j < 2; j++) roffW[j] = (wn + 16 * j + r16) * 128;

    f32x4 accg[4][2] = {};
    f32x4 accu[4][2] = {};
    const int NS = K >> 6;

    // prologue: sub-tile 0 -> slot 0, sub-tile 1 -> slot 1 (6 issues each)
#pragma unroll
    for (int s = 0; s < 2; s++) {
        bf16* d = dl + s * SLOT;
        const bf16* qa = pA + (size_t)s * 64;
        const bf16* qg = pG + (size_t)s * 64;
        const bf16* qu = pU + (size_t)s * 64;
        gload_lds16(qa,       d);
        gload_lds16(qg,       d + STRM);
        gload_lds16(qu,       d + 2 * STRM);
        gload_lds16(qa + rsk, d + 4096);
        gload_lds16(qg + rsk, d + STRM + 4096);
        gload_lds16(qu + rsk, d + 2 * STRM + 4096);
    }

    int cs = 0, ss = 2;
    for (int s = 0; s < NS; s++) {
        const int sp = (s + 2 < NS) ? (s + 2) : (NS - 1);   // clamped prefetch
        const size_t ko = (size_t)sp * 64;
        const bf16* qa = pA + ko;
        const bf16* qg = pG + ko;
        const bf16* qu = pU + ko;
        bf16* d = dl + ss * SLOT;
        const char* cb = lb + (size_t)cs * (SLOT * 2);

        asm volatile("s_waitcnt vmcnt(6)" ::: "memory");  // sub-tile s resident (own wave)
        __builtin_amdgcn_s_barrier();                     // collective; frees slot ss
        __builtin_amdgcn_sched_barrier(0);

        // ---- phase A (ks=0) ----
        gload_lds16(qa, d);
        gload_lds16(qg, d + STRM);
        gload_lds16(qu, d + 2 * STRM);
        {
            short8 a[4], g[2], u[2];
#pragma unroll
            for (int i = 0; i < 4; i++)
                a[i] = *(const short8*)(cb + roffA[i] + cswz0);
#pragma unroll
            for (int j = 0; j < 2; j++) {
                g[j] = *(const short8*)(cb + (STRM * 2) + roffW[j] + cswz0);
                u[j] = *(const short8*)(cb + (STRM * 4) + roffW[j] + cswz0);
            }
            asm volatile("s_waitcnt lgkmcnt(0)" ::: "memory");
            __builtin_amdgcn_sched_barrier(0);
            __builtin_amdgcn_s_setprio(1);
#pragma unroll
            for (int i = 0; i < 4; i++)
#pragma unroll
                for (int j = 0; j < 2; j++) {
                    accg[i][j] = __builtin_amdgcn_mfma_f32_16x16x32_bf16(a[i], g[j], accg[i][j], 0, 0, 0);
                    accu[i][j] = __builtin_amdgcn_mfma_f32_16x16x32_bf16(a[i], u[j], accu[i][j], 0, 0, 0);
                }
            __builtin_amdgcn_s_setprio(0);
        }

        // ---- phase B (ks=1) ----
        gload_lds16(qa + rsk, d + 4096);
        gload_lds16(qg + rsk, d + STRM + 4096);
        gload_lds16(qu + rsk, d + 2 * STRM + 4096);
        {
            short8 a[4], g[2], u[2];
#pragma unroll
            for (int i = 0; i < 4; i++)
                a[i] = *(const short8*)(cb + roffA[i] + cswz1);
#pragma unroll
            for (int j = 0; j < 2; j++) {
                g[j] = *(const short8*)(cb + (STRM * 2) + roffW[j] + cswz1);
                u[j] = *(const short8*)(cb + (STRM * 4) + roffW[j] + cswz1);
            }
            asm volatile("s_waitcnt lgkmcnt(0)" ::: "memory");
            __builtin_amdgcn_sched_barrier(0);
            __builtin_amdgcn_s_setprio(1);
#pragma unroll
            for (int i = 0; i < 4; i++)
#pragma unroll
                for (int j = 0; j < 2; j++) {
                    accg[i][j] = __builtin_amdgcn_mfma_f32_16x16x32_bf16(a[i], g[j], accg[i][j], 0, 0, 0);
                    accu[i][j] = __builtin_amdgcn_mfma_f32_16x16x32_bf16(a[i], u[j], accu[i][j], 0, 0, 0);
                }
            __builtin_amdgcn_s_setprio(0);
        }

        cs = (cs == 2) ? 0 : cs + 1;
        ss = (ss == 2) ? 0 : ss + 1;
    }
    asm volatile("s_waitcnt vmcnt(0)" ::: "memory");   // drain clamped tail loads

    // epilogue: h = g*sigmoid(g)*u. C/D: col=lane&15, row=(lane>>4)*4+r
#pragma unroll
    for (int i = 0; i < 4; i++) {
        const int rowb = m0 + wm + 16 * i + (lane >> 4) * 4;
#pragma unroll
        for (int j = 0; j < 2; j++) {
            const int col = n0 + wn + 16 * j + r16;
#pragma unroll
            for (int r = 0; r < 4; r++) {
                float g = accg[i][j][r];
                float u = accu[i][j][r];
                float h = g * u / (1.0f + __expf(-g));
                H[(size_t)(rowb + r) * N + col] = __float2bfloat16(h);
            }
        }
    }
}

// ---------------------------------------------------------------------------
// gemm8_down: OUT (+)= Ha @ Bs[:, col0:+Ka]^T (+ Hb @ Br^T if Kb>0), f32 out.
// Tile BM=128 x BN=256, waves 2M x 4N, per-wave 64x64 output.
// LDS slot = A(128x64) + B(256x64) = 48 KB; 3 slots = 144 KB. bf16-only B.
// ---------------------------------------------------------------------------
__global__ __launch_bounds__(512) void gemm8_down(
    const bf16* __restrict__ Ha, const bf16* __restrict__ Bs,
    long ldBs, long col0,
    const bf16* __restrict__ Hb, const bf16* __restrict__ Br,
    long ldBr, float* __restrict__ OUT,
    int M, int N, int Ka, int Kb, int acc)
{
    constexpr int STRM = 128 * 64;
    constexpr int SLOT = 3 * STRM;
    __shared__ __align__(16) bf16 lds[3 * SLOT];

    const int tid  = threadIdx.x;
    const int lane = tid & 63;
    const int wave = tid >> 6;
    const int n0 = blockIdx.x * 256;
    const int m0 = blockIdx.y * 128;

    const int srow = tid >> 3;
    const int scol = (((tid & 7) ^ (srow & 7)) << 3);
    const bf16* pA1 = Ha + (size_t)(m0 + srow) * Ka + scol;
    const bf16* pB1 = Bs + (size_t)(n0 + srow) * ldBs + col0 + scol;
    const bf16* pA2 = Hb + (size_t)(m0 + srow) * Kb + scol;
    const bf16* pB2 = Br + (size_t)(n0 + srow) * ldBr + scol;
    const size_t rA1 = (size_t)64 * Ka, rB1 = (size_t)64 * ldBs;
    const size_t rA2 = (size_t)64 * Kb, rB2 = (size_t)64 * ldBr;
    bf16* dl = lds + tid * 8;

    const int wm = (wave >> 2) * 64;   // 0,64
    const int wn = (wave & 3) * 64;    // 0,64,128,192
    const int r16 = lane & 15;
    const int kq  = lane >> 4;
    const int cswz0 = ((kq       ^ (lane & 7)) << 4);
    const int cswz1 = (((4 + kq) ^ (lane & 7)) << 4);
    const char* lb = (const char*)lds;

    int roffA[4], roffB[4];
#pragma unroll
    for (int i = 0; i < 4; i++) roffA[i] = (wm + 16 * i + r16) * 128;
#pragma unroll
    for (int j = 0; j < 4; j++) roffB[j] = (wn + 16 * j + r16) * 128;

    f32x4 acc4[4][4] = {};
    const int NS1 = Ka >> 6;
    const int NS  = NS1 + (Kb >> 6);

    // prologue (sub-tiles 0,1 are always in segment 1; NS1 >= 2)
#pragma unroll
    for (int s = 0; s < 2; s++) {
        bf16* d = dl + s * SLOT;
        const bf16* qa = pA1 + (size_t)s * 64;
        const bf16* qb = pB1 + (size_t)s * 64;
        gload_lds16(qa,           d);                      // A rows 0-63
        gload_lds16(qb,           d + STRM);               // B rows 0-63
        gload_lds16(qb + rB1,     d + STRM + 4096);        // B rows 64-127
        gload_lds16(qa + rA1,     d + 4096);               // A rows 64-127
        gload_lds16(qb + 2 * rB1, d + 2 * STRM);           // B rows 128-191
        gload_lds16(qb + 3 * rB1, d + 2 * STRM + 4096);    // B rows 192-255
    }

    int cs = 0, ss = 2;
    for (int s = 0; s < NS; s++) {
        const int sp = (s + 2 < NS) ? (s + 2) : (NS - 1);
        const bf16 *qa, *qb; size_t ra, rb;
        if (sp < NS1) {
            size_t ko = (size_t)sp * 64;
            qa = pA1 + ko; qb = pB1 + ko; ra = rA1; rb = rB1;
        } else {
            size_t ko = (size_t)(sp - NS1) * 64;
            qa = pA2 + ko; qb = pB2 + ko; ra = rA2; rb = rB2;
        }
        bf16* d = dl + ss * SLOT;
        const char* cb = lb + (size_t)cs * (SLOT * 2);

        asm volatile("s_waitcnt vmcnt(6)" ::: "memory");
        __builtin_amdgcn_s_barrier();
        __builtin_amdgcn_sched_barrier(0);

        // ---- phase A (ks=0) ----
        gload_lds16(qa,      d);
        gload_lds16(qb,      d + STRM);
        gload_lds16(qb + rb, d + STRM + 4096);
        {
            short8 a[4], b[4];
#pragma unroll
            for (int i = 0; i < 4; i++)
                a[i] = *(const short8*)(cb + roffA[i] + cswz0);
#pragma unroll
            for (int j = 0; j < 4; j++)
                b[j] = *(const short8*)(cb + (STRM * 2) + roffB[j] + cswz0);
            asm volatile("s_waitcnt lgkmcnt(0)" ::: "memory");
            __builtin_amdgcn_sched_barrier(0);
            __builtin_amdgcn_s_setprio(1);
#pragma unroll
            for (int i = 0; i < 4; i++)
#pragma unroll
                for (int j = 0; j < 4; j++)
                    acc4[i][j] = __builtin_amdgcn_mfma_f32_16x16x32_bf16(a[i], b[j], acc4[i][j], 0, 0, 0);
            __builtin_amdgcn_s_setprio(0);
        }

        // ---- phase B (ks=1) ----
        gload_lds16(qa + ra,     d + 4096);
        gload_lds16(qb + 2 * rb, d + 2 * STRM);
        gload_lds16(qb + 3 * rb, d + 2 * STRM + 4096);
        {
            short8 a[4], b[4];
#pragma unroll
            for (int i = 0; i < 4; i++)
                a[i] = *(const short8*)(cb + roffA[i] + cswz1);
#pragma unroll
            for (int j = 0; j < 4; j++)
                b[j] = *(const short8*)(cb + (STRM * 2) + roffB[j] + cswz1);
            asm volatile("s_waitcnt lgkmcnt(0)" ::: "memory");
            __builtin_amdgcn_sched_barrier(0);
            __builtin_amdgcn_s_setprio(1);
#pragma unroll
            for (int i = 0; i < 4; i++)
#pragma unroll
                for (int j = 0; j < 4; j++)
                    acc4[i][j] = __builtin_amdgcn_mfma_f32_16x16x32_bf16(a[i], b[j], acc4[i][j], 0, 0, 0);
            __builtin_amdgcn_s_setprio(0);
        }

        cs = (cs == 2) ? 0 : cs + 1;
        ss = (ss == 2) ? 0 : ss + 1;
    }
    asm volatile("s_waitcnt vmcnt(0)" ::: "memory");

#pragma unroll
    for (int i = 0; i < 4; i++) {
        const int rowb = m0 + wm + 16 * i + (lane >> 4) * 4;
#pragma unroll
        for (int j = 0; j < 4; j++) {
            const int col = n0 + wn + 16 * j + r16;
#pragma unroll
            for (int r = 0; r < 4; r++) {
                const size_t idx = (size_t)(rowb + r) * N + col;
                float v = acc4[i][j][r];
                OUT[idx] = acc ? (OUT[idx] + v) : v;
            }
        }
    }
}

// ===========================================================================
// Round-1 kernels kept as fallbacks (proven correct).
// ===========================================================================
__global__ __launch_bounds__(256) void gemm_gu_bb(
    const bf16* __restrict__ X, const bf16* __restrict__ Wg,
    const bf16* __restrict__ Wu, bf16* __restrict__ H,
    int M, int N, int K)
{
    __shared__ bf16 sA[128 * 32];
    __shared__ bf16 sG[64 * 32];
    __shared__ bf16 sU[64 * 32];

    const int tid  = threadIdx.x;
    const int lane = tid & 63;
    const int wave = tid >> 6;
    const int n0 = blockIdx.x * 64;
    const int m0 = blockIdx.y * 128;

    const int srow = tid >> 2;
    const int scol = (tid & 3) * 8;
    const bf16* ga = X  + (size_t)(m0 + srow) * K + scol;
    const bf16* gg = Wg + (size_t)(n0 + srow) * K + scol;
    const bf16* gu = Wu + (size_t)(n0 + srow) * K + scol;
    const size_t rowskip = (size_t)64 * K;
    bf16* la = sA + tid * 8;
    bf16* lg = sG + tid * 8;
    bf16* lu = sU + tid * 8;

    const int wm  = (wave >> 1) * 64;
    const int wn  = (wave & 1) * 32;
    const int r16 = lane & 15;
    const int kq8 = (lane >> 4) * 8;

    f32x4 accg[4][2] = {};
    f32x4 accu[4][2] = {};

    for (int k0 = 0; k0 < K; k0 += 32) {
        gload_lds16(ga,           la);
        gload_lds16(ga + rowskip, la + 2048);
        gload_lds16(gg,           lg);
        gload_lds16(gu,           lu);
        ga += 32; gg += 32; gu += 32;
        __syncthreads();

        short8 af[4], bg[2], bu[2];
#pragma unroll
        for (int i = 0; i < 4; i++)
            af[i] = *reinterpret_cast<const short8*>(sA + (wm + 16 * i + r16) * 32 + kq8);
#pragma unroll
        for (int j = 0; j < 2; j++) {
            bg[j] = *reinterpret_cast<const short8*>(sG + (wn + 16 * j + r16) * 32 + kq8);
            bu[j] = *reinterpret_cast<const short8*>(sU + (wn + 16 * j + r16) * 32 + kq8);
        }
#pragma unroll
        for (int i = 0; i < 4; i++)
#pragma unroll
            for (int j = 0; j < 2; j++) {
                accg[i][j] = __builtin_amdgcn_mfma_f32_16x16x32_bf16(af[i], bg[j], accg[i][j], 0, 0, 0);
                accu[i][j] = __builtin_amdgcn_mfma_f32_16x16x32_bf16(af[i], bu[j], accu[i][j], 0, 0, 0);
            }
        __syncthreads();
    }

#pragma unroll
    for (int i = 0; i < 4; i++) {
        const int rowb = m0 + wm + 16 * i + (lane >> 4) * 4;
#pragma unroll
        for (int j = 0; j < 2; j++) {
            const int col = n0 + wn + 16 * j + r16;
#pragma unroll
            for (int r = 0; r < 4; r++) {
                float g = accg[i][j][r];
                float u = accu[i][j][r];
                float h = g * u / (1.0f + __expf(-g));
                H[(size_t)(rowb + r) * N + col] = __float2bfloat16(h);
            }
        }
    }
}

__global__ __launch_bounds__(256) void gemm_gu_f32(
    const float* __restrict__ X, const float* __restrict__ Wg,
    const float* __restrict__ Wu, bf16* __restrict__ H,
    int M, int N, int K)
{
    __shared__ bf16 sA[128 * 32];
    __shared__ bf16 sG[64 * 32];
    __shared__ bf16 sU[64 * 32];

    const int tid  = threadIdx.x;
    const int lane = tid & 63;
    const int wave = tid >> 6;
    const int n0 = blockIdx.x * 64;
    const int m0 = blockIdx.y * 128;

    const int srow = tid >> 2;
    const int scol = (tid & 3) * 8;

    const int wm  = (wave >> 1) * 64;
    const int wn  = (wave & 1) * 32;
    const int r16 = lane & 15;
    const int kq8 = (lane >> 4) * 8;

    f32x4 accg[4][2] = {};
    f32x4 accu[4][2] = {};

    for (int k0 = 0; k0 < K; k0 += 32) {
#pragma unroll
        for (int seg = 0; seg < 2; seg++) {
            const int row = srow + 64 * seg;
            const float* pa = X + (size_t)(m0 + row) * K + k0 + scol;
            float4 a0 = *(const float4*)pa, a1 = *(const float4*)(pa + 4);
            *(short8*)(sA + row * 32 + scol) = cvt8(a0, a1);
        }
        {
            const float* pg = Wg + (size_t)(n0 + srow) * K + k0 + scol;
            const float* pu = Wu + (size_t)(n0 + srow) * K + k0 + scol;
            float4 g0 = *(const float4*)pg, g1 = *(const float4*)(pg + 4);
            float4 u0 = *(const float4*)pu, u1 = *(const float4*)(pu + 4);
            *(short8*)(sG + srow * 32 + scol) = cvt8(g0, g1);
            *(short8*)(sU + srow * 32 + scol) = cvt8(u0, u1);
        }
        __syncthreads();

        short8 af[4], bg[2], bu[2];
#pragma unroll
        for (int i = 0; i < 4; i++)
            af[i] = *reinterpret_cast<const short8*>(sA + (wm + 16 * i + r16) * 32 + kq8);
#pragma unroll
        for (int j = 0; j < 2; j++) {
            bg[j] = *reinterpret_cast<const short8*>(sG + (wn + 16 * j + r16) * 32 + kq8);
            bu[j] = *reinterpret_cast<const short8*>(sU + (wn + 16 * j + r16) * 32 + kq8);
        }
#pragma unroll
        for (int i = 0; i < 4; i++)
#pragma unroll
            for (int j = 0; j < 2; j++) {
                accg[i][j] = __builtin_amdgcn_mfma_f32_16x16x32_bf16(af[i], bg[j], accg[i][j], 0, 0, 0);
                accu[i][j] = __builtin_amdgcn_mfma_f32_16x16x32_bf16(af[i], bu[j], accu[i][j], 0, 0, 0);
            }
        __syncthreads();
    }

#pragma unroll
    for (int i = 0; i < 4; i++) {
        const int rowb = m0 + wm + 16 * i + (lane >> 4) * 4;
#pragma unroll
        for (int j = 0; j < 2; j++) {
            const int col = n0 + wn + 16 * j + r16;
#pragma unroll
            for (int r = 0; r < 4; r++) {
                float g = accg[i][j][r];
                float u = accu[i][j][r];
                float h = g * u / (1.0f + __expf(-g));
                H[(size_t)(rowb + r) * N + col] = __float2bfloat16(h);
            }
        }
    }
}

__global__ __launch_bounds__(256) void gemm_down2(
    const bf16* __restrict__ Ha, const bf16* __restrict__ Bs16,
    const float* __restrict__ Bs32, int sflag, long ldBs, long col0,
    const bf16* __restrict__ Hb, const bf16* __restrict__ Br16,
    const float* __restrict__ Br32, int rflag, long ldBr,
    float* __restrict__ OUT, int M, int N, int Ka, int Kb, int acc)
{
    __shared__ bf16 sA[128 * 32];
    __shared__ bf16 sB[128 * 32];

    const int tid  = threadIdx.x;
    const int lane = tid & 63;
    const int wave = tid >> 6;
    const int n0 = blockIdx.x * 128;
    const int m0 = blockIdx.y * 128;

    const int srow = tid >> 2;
    const int scol = (tid & 3) * 8;
    bf16* la = sA + tid * 8;
    bf16* lb = sB + tid * 8;

    const int wm  = (wave >> 1) * 64;
    const int wn  = (wave & 1) * 64;
    const int r16 = lane & 15;
    const int kq8 = (lane >> 4) * 8;

    f32x4 acc4[4][4] = {};

    {
        const bf16* ga = Ha + (size_t)(m0 + srow) * Ka + scol;
        const size_t rska = (size_t)64 * Ka;
        const bf16* gb = Bs16 + (size_t)(n0 + srow) * ldBs + col0 + scol;
        const size_t rskb = (size_t)64 * ldBs;
        for (int k0 = 0; k0 < Ka; k0 += 32) {
            gload_lds16(ga,        la);
            gload_lds16(ga + rska, la + 2048);
            ga += 32;
            if (sflag) {
                gload_lds16(gb,        lb);
                gload_lds16(gb + rskb, lb + 2048);
                gb += 32;
            } else {
#pragma unroll
                for (int seg = 0; seg < 2; seg++) {
                    const int row = srow + 64 * seg;
                    const float* pb = Bs32 + (size_t)(n0 + row) * ldBs + col0 + k0 + scol;
                    float4 b0 = *(const float4*)pb, b1 = *(const float4*)(pb + 4);
                    *(short8*)(sB + row * 32 + scol) = cvt8(b0, b1);
                }
            }
            __syncthreads();

            short8 af[4], bw[4];
#pragma unroll
            for (int i = 0; i < 4; i++)
                af[i] = *reinterpret_cast<const short8*>(sA + (wm + 16 * i + r16) * 32 + kq8);
#pragma unroll
            for (int j = 0; j < 4; j++)
                bw[j] = *reinterpret_cast<const short8*>(sB + (wn + 16 * j + r16) * 32 + kq8);
#pragma unroll
            for (int i = 0; i < 4; i++)
#pragma unroll
                for (int j = 0; j < 4; j++)
                    acc4[i][j] = __builtin_amdgcn_mfma_f32_16x16x32_bf16(af[i], bw[j], acc4[i][j], 0, 0, 0);
            __syncthreads();
        }
    }
    if (Kb > 0) {
        const bf16* ga = Hb + (size_t)(m0 + srow) * Kb + scol;
        const size_t rska = (size_t)64 * Kb;
        const bf16* gb = Br16 + (size_t)(n0 + srow) * ldBr + scol;
        const size_t rskb = (size_t)64 * ldBr;
        for (int k0 = 0; k0 < Kb; k0 += 32) {
            gload_lds16(ga,        la);
            gload_lds16(ga + rska, la + 2048);
            ga += 32;
            if (rflag) {
                gload_lds16(gb,        lb);
                gload_lds16(gb + rskb, lb + 2048);
                gb += 32;
            } else {
#pragma unroll
                for (int seg = 0; seg < 2; seg++) {
                    const int row = srow + 64 * seg;
                    const float* pb = Br32 + (size_t)(n0 + row) * ldBr + k0 + scol;
                    float4 b0 = *(const float4*)pb, b1 = *(const float4*)(pb + 4);
                    *(short8*)(sB + row * 32 + scol) = cvt8(b0, b1);
                }
            }
            __syncthreads();

            short8 af[4], bw[4];
#pragma unroll
            for (int i = 0; i < 4; i++)
                af[i] = *reinterpret_cast<const short8*>(sA + (wm + 16 * i + r16) * 32 + kq8);
#pragma unroll
            for (int j = 0; j < 4; j++)
                bw[j] = *reinterpret_cast<const short8*>(sB + (wn + 16 * j + r16) * 32 + kq8);
#pragma unroll
            for (int i = 0; i < 4; i++)
#pragma unroll
                for (int j = 0; j < 4; j++)
                    acc4[i][j] = __builtin_amdgcn_mfma_f32_16x16x32_bf16(af[i], bw[j], acc4[i][j], 0, 0, 0);
            __syncthreads();
        }
    }

#pragma unroll
    for (int i = 0; i < 4; i++) {
        const int rowb = m0 + wm + 16 * i + (lane >> 4) * 4;
#pragma unroll
        for (int j = 0; j < 4; j++) {
            const int col = n0 + wn + 16 * j + r16;
#pragma unroll
            for (int r = 0; r < 4; r++) {
                const size_t idx = (size_t)(rowb + r) * N + col;
                float v = acc4[i][j][r];
                OUT[idx] = acc ? (OUT[idx] + v) : v;
            }
        }
    }
}

// ---------------------------------------------------------------------------
// launch: greedy ws allocation. Primary path (all bf16 buffers) uses the
// deep-pipelined kernels; otherwise fall back to round-1 logic.
// ---------------------------------------------------------------------------
extern "C" void kernel_launch(void* const* d_in, const int* in_sizes, int n_in,
                              void* d_out, int out_size, void* d_ws, size_t ws_size,
                              hipStream_t stream) {
    const float* x       = (const float*)d_in[0];
    // d_in[1] = router_weight: dead (topk_idx < 8 always => comb_w == 1)
    const float* sh_gate = (const float*)d_in[2];
    const float* sh_up   = (const float*)d_in[3];
    const float* sh_down = (const float*)d_in[4];
    const float* r_gate  = (const float*)d_in[5];
    const float* r_up    = (const float*)d_in[6];
    const float* r_down  = (const float*)d_in[7];
    float* out = (float*)d_out;

    auto cast = [&](const float* in, bf16* o, size_t n) {
        int n4 = (int)(n / 4);
        int blocks = (n4 + 255) / 256;
        if (blocks > 2048) blocks = 2048;
        cast_f32_to_bf16<<<dim3(blocks), dim3(256), 0, stream>>>(in, o, n4);
    };

    const size_t HS_MIN = (size_t)TOK * 128 * 2;
    size_t limit = (ws_size > HS_MIN) ? ws_size - HS_MIN : 0;
    size_t off = 0;
    auto take = [&](size_t bytes) -> bf16* {
        if (off + bytes <= limit) { bf16* p = (bf16*)((char*)d_ws + off); off += bytes; return p; }
        return nullptr;
    };

    bf16* Xb = take((size_t)TOK   * HID * 2);
    bf16* Gs = take((size_t)INTER * HID * 2);
    bf16* Us = take((size_t)INTER * HID * 2);
    bf16* Hr = take((size_t)TOK   * MOE_I * 2);

    if (Xb && Gs && Us && Hr) {
        bf16* Ds = take((size_t)INTER * HID * 2);
        bf16* Gr = take((size_t)MOE_I * HID * 2);
        bf16* Ur = take((size_t)MOE_I * HID * 2);
        bf16* Dr = take((size_t)MOE_I * HID * 2);

        size_t remain = ws_size - off;
        int Nc = 128;
        const int cands[7] = {8192, 4096, 2048, 1024, 512, 256, 128};
        for (int i = 0; i < 7; i++)
            if ((size_t)TOK * cands[i] * 2 <= remain) { Nc = cands[i]; break; }
        bf16* Hs = (bf16*)((char*)d_ws + off);

        cast(x,       Xb, (size_t)TOK   * HID);
        cast(sh_gate, Gs, (size_t)INTER * HID);
        cast(sh_up,   Us, (size_t)INTER * HID);
        if (Ds) cast(sh_down, Ds, (size_t)INTER * HID);
        if (Gr) cast(r_gate,  Gr, (size_t)MOE_I * HID);
        if (Ur) cast(r_up,    Ur, (size_t)MOE_I * HID);
        if (Dr) cast(r_down,  Dr, (size_t)MOE_I * HID);

        if (Ds && Gr && Ur && Dr) {
            // ---- primary: deep-pipelined path ----
            gemm8_gu<<<dim3(MOE_I / 128, TOK / 128), dim3(512), 0, stream>>>(
                Xb, Gr, Ur, Hr, TOK, MOE_I, HID);
            const int nch = INTER / Nc;
            for (int c = 0; c < nch; c++) {
                gemm8_gu<<<dim3(Nc / 128, TOK / 128), dim3(512), 0, stream>>>(
                    Xb, Gs + (size_t)c * Nc * HID, Us + (size_t)c * Nc * HID,
                    Hs, TOK, Nc, HID);
                gemm8_down<<<dim3(HID / 256, TOK / 128), dim3(512), 0, stream>>>(
                    Hs, Ds, (long)INTER, (long)c * Nc,
                    Hr, Dr, (long)MOE_I,
                    out, TOK, HID, Nc, (c == 0) ? MOE_I : 0, (c == 0) ? 0 : 1);
            }
            return;
        }

        // ---- round-1 mixed path ----
        if (Gr && Ur)
            gemm_gu_bb<<<dim3(MOE_I / 64, TOK / 128), dim3(256), 0, stream>>>(
                Xb, Gr, Ur, Hr, TOK, MOE_I, HID);
        else
            gemm_gu_f32<<<dim3(MOE_I / 64, TOK / 128), dim3(256), 0, stream>>>(
                x, r_gate, r_up, Hr, TOK, MOE_I, HID);

        const int nch = INTER / Nc;
        for (int c = 0; c < nch; c++) {
            gemm_gu_bb<<<dim3(Nc / 64, TOK / 128), dim3(256), 0, stream>>>(
                Xb, Gs + (size_t)c * Nc * HID, Us + (size_t)c * Nc * HID,
                Hs, TOK, Nc, HID);
            gemm_down2<<<dim3(HID / 128, TOK / 128), dim3(256), 0, stream>>>(
                Hs, Ds, sh_down, Ds ? 1 : 0, (long)INTER, (long)c * Nc,
                Hr, Dr, r_down, Dr ? 1 : 0, (long)MOE_I,
                out, TOK, HID, Nc, (c == 0) ? MOE_I : 0, (c == 0) ? 0 : 1);
        }
        return;
    }

    // ---- full fallback: fp32 fused-cast everywhere ----
    {
        const size_t hrBytes = (size_t)TOK * MOE_I * 2;
        int Nc = 128;
        const int cands[6] = {8192, 4096, 2048, 1024, 512, 256};
        for (int i = 0; i < 6; i++)
            if ((size_t)TOK * cands[i] * 2 + hrBytes <= ws_size) { Nc = cands[i]; break; }
        bf16* Hs = (bf16*)d_ws;
        bf16* Hr2 = Hs + (size_t)TOK * Nc;

        gemm_gu_f32<<<dim3(MOE_I / 64, TOK / 128), dim3(256), 0, stream>>>(
            x, r_gate, r_up, Hr2, TOK, MOE_I, HID);
        const int nch = INTER / Nc;
        for (int c = 0; c < nch; c++) {
            gemm_gu_f32<<<dim3(Nc / 64, TOK / 128), dim3(256), 0, stream>>>(
                x, sh_gate + (size_t)c * Nc * HID, sh_up + (size_t)c * Nc * HID,
                Hs, TOK, Nc, HID);
            gemm_down2<<<dim3(HID / 128, TOK / 128), dim3(256), 0, stream>>>(
                Hs, nullptr, sh_down, 0, (long)INTER, (long)c * Nc,
                Hr2, nullptr, r_down, 0, (long)MOE_I,
                out, TOK, HID, Nc, (c == 0) ? MOE_I : 0, (c == 0) ? 0 : 1);
        }
    }
}